// Round 1
// baseline (805.668 us; speedup 1.0000x reference)
//
#include <hip/hip_runtime.h>
#include <stdint.h>

using f32x4  = __attribute__((ext_vector_type(4))) float;
using bf16x8 = __attribute__((ext_vector_type(8))) short;

#define DEV static __device__ __forceinline__

DEV unsigned short f2bf(float f){
  union { float f; unsigned int u; } c; c.f = f;
  unsigned int u = c.u;
  u += 0x7FFFu + ((u >> 16) & 1u);   // round-to-nearest-even
  return (unsigned short)(u >> 16);
}

DEV void gld_lds16(const void* g, void* l){
  __builtin_amdgcn_global_load_lds(
      (const __attribute__((address_space(1))) void*)g,
      (__attribute__((address_space(3))) void*)l, 16, 0, 0);
}

// ---------------------------------------------------------------- converts
__global__ __launch_bounds__(256) void cvt_f32_bf16(
    const float* __restrict__ in, unsigned short* __restrict__ out, int n){
  for (int i = (blockIdx.x*256 + threadIdx.x)*4; i < n; i += gridDim.x*1024){
    float4 v = *(const float4*)(in + i);
    ushort4 o; o.x=f2bf(v.x); o.y=f2bf(v.y); o.z=f2bf(v.z); o.w=f2bf(v.w);
    *(ushort4*)(out + i) = o;
  }
}

// ---------------------------------------------------------------- GEMM
// C[M,N] = alpha * A[M,K] @ B[N,K]^T + bias; A bf16 (or fp32, converted in
// staging), B bf16. m97 structure: 128x128 tile, BK=32, 4 waves (2x2),
// global_load_lds width 16, mfma_f32_16x16x32_bf16.
template<bool A_F32, bool OUT_BF16, bool RELU, bool HAS_BIAS>
__global__ __launch_bounds__(256, 2)
void gemm_bt(const void* __restrict__ Ap, const unsigned short* __restrict__ Bp,
             const float* __restrict__ bias, void* __restrict__ Cp,
             int N, int K, float alpha, long sAz, long sBz, long sCz)
{
  constexpr int BM = 128, BN = 128, BK = 32;
  __shared__ __align__(16) unsigned short As[BM*BK];
  __shared__ __align__(16) unsigned short Bs[BN*BK];
  const int tid  = threadIdx.x;
  const int lane = tid & 63;
  const int wid  = tid >> 6;
  const int wr   = wid >> 1, wc = wid & 1;
  const int mrow = lane & 15;
  const int krow = lane >> 4;

  const unsigned short* Bb = Bp + sBz*blockIdx.z + (long)blockIdx.x*BN*K;

  f32x4 acc[4][4] = {};

  for (int k0 = 0; k0 < K; k0 += BK){
    // ---- stage A tile (128 x 32)
    if constexpr (A_F32){
      const float* Ab = (const float*)Ap + sAz*blockIdx.z + (long)blockIdx.y*BM*K;
      #pragma unroll
      for (int it = 0; it < 4; ++it){
        int ci  = it*256 + tid;          // float4 chunk 0..1023
        int row = ci >> 3;
        int col = (ci & 7) * 4;
        float4 v = *(const float4*)(Ab + (long)row*K + k0 + col);
        ushort4 o; o.x=f2bf(v.x); o.y=f2bf(v.y); o.z=f2bf(v.z); o.w=f2bf(v.w);
        *(ushort4*)&As[ci*4] = o;
      }
    } else {
      const unsigned short* Ab = (const unsigned short*)Ap + sAz*blockIdx.z + (long)blockIdx.y*BM*K;
      #pragma unroll
      for (int it = 0; it < 2; ++it){
        int ci  = it*256 + tid;          // 16B chunk 0..511
        int row = ci >> 2;
        int col = (ci & 3) * 8;
        gld_lds16(Ab + (long)row*K + k0 + col, (char*)As + it*4096 + wid*1024);
      }
    }
    // ---- stage B tile (128 x 32)
    #pragma unroll
    for (int it = 0; it < 2; ++it){
      int ci  = it*256 + tid;
      int row = ci >> 2;
      int col = (ci & 3) * 8;
      gld_lds16(Bb + (long)row*K + k0 + col, (char*)Bs + it*4096 + wid*1024);
    }
    __syncthreads();

    bf16x8 a[4], b[4];
    #pragma unroll
    for (int mi = 0; mi < 4; ++mi)
      a[mi] = *(const bf16x8*)&As[(wr*64 + mi*16 + mrow)*BK + krow*8];
    #pragma unroll
    for (int ni = 0; ni < 4; ++ni)
      b[ni] = *(const bf16x8*)&Bs[(wc*64 + ni*16 + mrow)*BK + krow*8];
    #pragma unroll
    for (int mi = 0; mi < 4; ++mi)
      #pragma unroll
      for (int ni = 0; ni < 4; ++ni)
        acc[mi][ni] = __builtin_amdgcn_mfma_f32_16x16x32_bf16(a[mi], b[ni], acc[mi][ni], 0, 0, 0);
    __syncthreads();
  }

  // ---- epilogue: D layout row=(lane>>4)*4+r, col=lane&15  [m89-verified]
  long cb = sCz*blockIdx.z;
  int row0 = blockIdx.y*BM + wr*64;
  int col0 = blockIdx.x*BN + wc*64;
  #pragma unroll
  for (int mi = 0; mi < 4; ++mi){
    #pragma unroll
    for (int ni = 0; ni < 4; ++ni){
      int col = col0 + ni*16 + mrow;
      float bv = HAS_BIAS ? bias[col] : 0.f;
      #pragma unroll
      for (int r = 0; r < 4; ++r){
        int row = row0 + mi*16 + krow*4 + r;
        float v = acc[mi][ni][r]*alpha + bv;
        if (RELU) v = fmaxf(v, 0.f);
        if (OUT_BF16) ((unsigned short*)Cp)[cb + (long)row*N + col] = f2bf(v);
        else          ((float*)Cp)[cb + (long)row*N + col] = v;
      }
    }
  }
}

// ---------------------------------------------------------------- V transpose
// V[g][j][e] (2048x128 bf16) -> Vt[g][e][j] (128x2048 bf16)
__global__ __launch_bounds__(256) void transpose_v(
    const unsigned short* __restrict__ V, unsigned short* __restrict__ Vt){
  __shared__ unsigned short t[32][33];
  int g = blockIdx.z;
  int j0 = blockIdx.x*32, e0 = blockIdx.y*32;
  int tx = threadIdx.x, ty = threadIdx.y;      // 32 x 8
  const unsigned short* Vg = V + (long)g*262144;
  unsigned short* Vtg = Vt + (long)g*262144;
  #pragma unroll
  for (int i = 0; i < 4; ++i)
    t[ty + 8*i][tx] = Vg[(long)(j0 + ty + 8*i)*128 + e0 + tx];
  __syncthreads();
  #pragma unroll
  for (int i = 0; i < 4; ++i)
    Vtg[(long)(e0 + ty + 8*i)*2048 + j0 + tx] = t[tx][ty + 8*i];
}

// ---------------------------------------------------------------- softmax
// in-place row softmax over 2048-wide rows (one block per row)
__global__ __launch_bounds__(256) void softmax_rows(float* __restrict__ S){
  long base = (long)blockIdx.x * 2048;
  int tid = threadIdx.x, lane = tid & 63, wid = tid >> 6;
  __shared__ float redm[4], reds[4];

  float4 v0 = *(const float4*)(S + base + tid*8);
  float4 v1 = *(const float4*)(S + base + tid*8 + 4);
  float m = fmaxf(fmaxf(fmaxf(v0.x,v0.y), fmaxf(v0.z,v0.w)),
                  fmaxf(fmaxf(v1.x,v1.y), fmaxf(v1.z,v1.w)));
  #pragma unroll
  for (int off = 32; off > 0; off >>= 1) m = fmaxf(m, __shfl_xor(m, off, 64));
  if (lane == 0) redm[wid] = m;
  __syncthreads();
  m = fmaxf(fmaxf(redm[0], redm[1]), fmaxf(redm[2], redm[3]));

  float e[8];
  e[0]=__expf(v0.x-m); e[1]=__expf(v0.y-m); e[2]=__expf(v0.z-m); e[3]=__expf(v0.w-m);
  e[4]=__expf(v1.x-m); e[5]=__expf(v1.y-m); e[6]=__expf(v1.z-m); e[7]=__expf(v1.w-m);
  float s = ((e[0]+e[1])+(e[2]+e[3])) + ((e[4]+e[5])+(e[6]+e[7]));
  #pragma unroll
  for (int off = 32; off > 0; off >>= 1) s += __shfl_xor(s, off, 64);
  if (lane == 0) reds[wid] = s;
  __syncthreads();
  s = (reds[0]+reds[1]) + (reds[2]+reds[3]);

  float inv = 1.f / s;
  v0.x=e[0]*inv; v0.y=e[1]*inv; v0.z=e[2]*inv; v0.w=e[3]*inv;
  v1.x=e[4]*inv; v1.y=e[5]*inv; v1.z=e[6]*inv; v1.w=e[7]*inv;
  *(float4*)(S + base + tid*8)     = v0;
  *(float4*)(S + base + tid*8 + 4) = v1;
}

// ---------------------------------------------------------------- LayerNorm
// out = LN(X + R) * gamma + beta over D=1024; one block per row
DEV float block_sum256(float v, float* red){
  #pragma unroll
  for (int off = 32; off > 0; off >>= 1) v += __shfl_xor(v, off, 64);
  int lane = threadIdx.x & 63, wid = threadIdx.x >> 6;
  if (lane == 0) red[wid] = v;
  __syncthreads();
  return (red[0]+red[1]) + (red[2]+red[3]);
}

template<bool WRITE_F32, bool WRITE_BF>
__global__ __launch_bounds__(256) void ln_residual(
    const float* __restrict__ X, const float* __restrict__ R,
    const float* __restrict__ gamma, const float* __restrict__ beta,
    float* __restrict__ outf, unsigned short* __restrict__ outb){
  __shared__ float red1[4], red2[4];
  long base = (long)blockIdx.x * 1024;
  int tid = threadIdx.x;
  float4 x = *(const float4*)(X + base + tid*4);
  float4 r = *(const float4*)(R + base + tid*4);
  float v[4] = {x.x+r.x, x.y+r.y, x.z+r.z, x.w+r.w};
  float s = (v[0]+v[1]) + (v[2]+v[3]);
  s = block_sum256(s, red1);
  float mean = s * (1.f/1024.f);
  float d[4] = {v[0]-mean, v[1]-mean, v[2]-mean, v[3]-mean};
  float sq = (d[0]*d[0]+d[1]*d[1]) + (d[2]*d[2]+d[3]*d[3]);
  sq = block_sum256(sq, red2);
  float rstd = rsqrtf(sq*(1.f/1024.f) + 1e-5f);
  float4 g4 = *(const float4*)(gamma + tid*4);
  float4 b4 = *(const float4*)(beta  + tid*4);
  float o[4] = { d[0]*rstd*g4.x + b4.x, d[1]*rstd*g4.y + b4.y,
                 d[2]*rstd*g4.z + b4.z, d[3]*rstd*g4.w + b4.w };
  if (WRITE_F32){
    float4 o4; o4.x=o[0]; o4.y=o[1]; o4.z=o[2]; o4.w=o[3];
    *(float4*)(outf + base + tid*4) = o4;
  }
  if (WRITE_BF){
    ushort4 ob; ob.x=f2bf(o[0]); ob.y=f2bf(o[1]); ob.z=f2bf(o[2]); ob.w=f2bf(o[3]);
    *(ushort4*)(outb + base + tid*4) = ob;
  }
}

// ---------------------------------------------------------------- host
extern "C" void kernel_launch(void* const* d_in, const int* in_sizes, int n_in,
                              void* d_out, int out_size, void* d_ws, size_t ws_size,
                              hipStream_t stream){
  const float* X   = (const float*)d_in[0];
  const float* Wq  = (const float*)d_in[1];
  const float* bq  = (const float*)d_in[2];
  const float* Wk  = (const float*)d_in[3];
  const float* bk  = (const float*)d_in[4];
  const float* Wv  = (const float*)d_in[5];
  const float* bv  = (const float*)d_in[6];
  const float* Wo  = (const float*)d_in[7];
  const float* bo  = (const float*)d_in[8];
  const float* g1  = (const float*)d_in[9];
  const float* b1n = (const float*)d_in[10];
  const float* W1  = (const float*)d_in[11];
  const float* b1  = (const float*)d_in[12];
  const float* W2  = (const float*)d_in[13];
  const float* b2  = (const float*)d_in[14];
  const float* g2  = (const float*)d_in[15];
  const float* b2n = (const float*)d_in[16];

  const int M = 8192, D = 1024, F = 2048;
  const long YSZ = (long)M * D;               // 8388608
  float* y_out = (float*)d_out;
  float* atten = (float*)d_out + YSZ;         // 32 x 2048 x 2048 fp32

  char* w = (char*)d_ws;
  auto alloc = [&](size_t bytes){ char* p = w; w += (bytes + 255) & ~(size_t)255; return p; };
  unsigned short* Xbf   = (unsigned short*)alloc((size_t)M*D*2);
  unsigned short* Wqbf  = (unsigned short*)alloc((size_t)D*D*2);
  unsigned short* Wkbf  = (unsigned short*)alloc((size_t)D*D*2);
  unsigned short* Wvbf  = (unsigned short*)alloc((size_t)D*D*2);
  unsigned short* Wobf  = (unsigned short*)alloc((size_t)D*D*2);
  unsigned short* W1bf  = (unsigned short*)alloc((size_t)F*D*2);
  unsigned short* W2bf  = (unsigned short*)alloc((size_t)D*F*2);
  unsigned short* Qbf   = (unsigned short*)alloc((size_t)M*D*2);
  unsigned short* Kbf   = (unsigned short*)alloc((size_t)M*D*2);
  unsigned short* Vbf   = (unsigned short*)alloc((size_t)M*D*2);
  unsigned short* Vtbf  = (unsigned short*)alloc((size_t)M*D*2);
  unsigned short* CTXbf = (unsigned short*)alloc((size_t)M*D*2);
  unsigned short* Hbf   = (unsigned short*)alloc((size_t)M*D*2);
  unsigned short* F1bf  = (unsigned short*)alloc((size_t)M*F*2);
  float*          Hf    = (float*)alloc((size_t)M*D*4);
  float*          TMP   = (float*)alloc((size_t)M*D*4);

  auto cvt = [&](const float* src, unsigned short* dst, int n){
    int blocks = (n/4 + 255)/256; if (blocks > 4096) blocks = 4096;
    cvt_f32_bf16<<<blocks, 256, 0, stream>>>(src, dst, n);
  };
  cvt(X,  Xbf,  M*D);
  cvt(Wq, Wqbf, D*D);  cvt(Wk, Wkbf, D*D);  cvt(Wv, Wvbf, D*D);  cvt(Wo, Wobf, D*D);
  cvt(W1, W1bf, F*D);  cvt(W2, W2bf, D*F);

  dim3 blk(256);
  const float scale = 0.08838834764831845f;   // 128^-0.5

  // Q/K/V projections: [8192,1024] = X @ W^T + b  -> bf16
  gemm_bt<false,true,false,true><<<dim3(D/128, M/128, 1), blk, 0, stream>>>(Xbf, Wqbf, bq, Qbf, D, D, 1.f, 0, 0, 0);
  gemm_bt<false,true,false,true><<<dim3(D/128, M/128, 1), blk, 0, stream>>>(Xbf, Wkbf, bk, Kbf, D, D, 1.f, 0, 0, 0);
  gemm_bt<false,true,false,true><<<dim3(D/128, M/128, 1), blk, 0, stream>>>(Xbf, Wvbf, bv, Vbf, D, D, 1.f, 0, 0, 0);

  // V -> Vt per group (for PV's B operand, K-contiguous)
  transpose_v<<<dim3(64, 4, 32), dim3(32, 8), 0, stream>>>(Vbf, Vtbf);

  // S = scale * Qg @ Kg^T  (32 groups, 2048x2048, K=128) -> fp32 logits in d_out
  gemm_bt<false,false,false,false><<<dim3(16, 16, 32), blk, 0, stream>>>(
      Qbf, Kbf, nullptr, atten, 2048, 128, scale, 262144, 262144, 4194304);

  // softmax rows in place (65536 rows)
  softmax_rows<<<65536, 256, 0, stream>>>(atten);

  // context = atten @ Vt^T  (A fp32 converted in staging) -> bf16
  gemm_bt<true,true,false,false><<<dim3(1, 16, 32), blk, 0, stream>>>(
      atten, Vtbf, nullptr, CTXbf, 128, 2048, 1.f, 4194304, 262144, 262144);

  // out = ctx @ Wo^T + bo -> TMP fp32
  gemm_bt<false,false,false,true><<<dim3(D/128, M/128, 1), blk, 0, stream>>>(CTXbf, Wobf, bo, TMP, D, D, 1.f, 0, 0, 0);

  // h = LN1(X + out) -> Hf (fp32) + Hbf (bf16)
  ln_residual<true,true><<<M, 256, 0, stream>>>(X, TMP, g1, b1n, Hf, Hbf);

  // f1 = relu(h @ W1^T + b1) -> bf16
  gemm_bt<false,true,true,true><<<dim3(F/128, M/128, 1), blk, 0, stream>>>(Hbf, W1bf, b1, F1bf, F, D, 1.f, 0, 0, 0);

  // f = f1 @ W2^T + b2 -> TMP fp32
  gemm_bt<false,false,false,true><<<dim3(D/128, M/128, 1), blk, 0, stream>>>(F1bf, W2bf, b2, TMP, D, F, 1.f, 0, 0, 0);

  // y = LN2(h + f) -> d_out
  ln_residual<true,false><<<M, 256, 0, stream>>>(Hf, TMP, g2, b2n, y_out, nullptr);
}

// Round 2
// 695.118 us; speedup vs baseline: 1.1590x; 1.1590x over previous
//
#include <hip/hip_runtime.h>
#include <stdint.h>

using f32x4  = __attribute__((ext_vector_type(4))) float;
using bf16x8 = __attribute__((ext_vector_type(8))) short;
using bf16x4 = __attribute__((ext_vector_type(4))) short;

#define DEV static __device__ __forceinline__

DEV unsigned short f2bf(float f){
  union { float f; unsigned int u; } c; c.f = f;
  unsigned int u = c.u;
  u += 0x7FFFu + ((u >> 16) & 1u);   // round-to-nearest-even
  return (unsigned short)(u >> 16);
}
DEV float bf2f(unsigned short u){
  union { unsigned int u; float f; } c; c.u = ((unsigned int)u) << 16; return c.f;
}

DEV void gld_lds16(const void* g, void* l){
  __builtin_amdgcn_global_load_lds(
      (const __attribute__((address_space(1))) void*)g,
      (__attribute__((address_space(3))) void*)l, 16, 0, 0);
}

// ---------------------------------------------------------------- converts
__global__ __launch_bounds__(256) void cvt_f32_bf16(
    const float* __restrict__ in, unsigned short* __restrict__ out, int n){
  for (int i = (blockIdx.x*256 + threadIdx.x)*4; i < n; i += gridDim.x*1024){
    float4 v = *(const float4*)(in + i);
    ushort4 o; o.x=f2bf(v.x); o.y=f2bf(v.y); o.z=f2bf(v.z); o.w=f2bf(v.w);
    *(ushort4*)(out + i) = o;
  }
}

// ---------------------------------------------------------------- GEMM
// C[M,N] = A[M,K] @ B[N,K]^T (+bias) ; bf16 in, fp32 acc. m97 structure.
template<bool OUT_BF16, bool RELU, bool HAS_BIAS>
__global__ __launch_bounds__(256, 2)
void gemm_bt(const unsigned short* __restrict__ Ap, const unsigned short* __restrict__ Bp,
             const float* __restrict__ bias, void* __restrict__ Cp, int N, int K)
{
  constexpr int BM = 128, BN = 128, BK = 32;
  __shared__ __align__(16) unsigned short As[BM*BK];
  __shared__ __align__(16) unsigned short Bs[BN*BK];
  const int tid  = threadIdx.x;
  const int lane = tid & 63;
  const int wid  = tid >> 6;
  const int wr   = wid >> 1, wc = wid & 1;
  const int mrow = lane & 15;
  const int krow = lane >> 4;

  const unsigned short* Ab = Ap + (long)blockIdx.y*BM*K;
  const unsigned short* Bb = Bp + (long)blockIdx.x*BN*K;

  f32x4 acc[4][4] = {};

  for (int k0 = 0; k0 < K; k0 += BK){
    #pragma unroll
    for (int it = 0; it < 2; ++it){
      int ci  = it*256 + tid;
      int row = ci >> 2;
      int col = (ci & 3) * 8;
      gld_lds16(Ab + (long)row*K + k0 + col, (char*)As + it*4096 + wid*1024);
    }
    #pragma unroll
    for (int it = 0; it < 2; ++it){
      int ci  = it*256 + tid;
      int row = ci >> 2;
      int col = (ci & 3) * 8;
      gld_lds16(Bb + (long)row*K + k0 + col, (char*)Bs + it*4096 + wid*1024);
    }
    __syncthreads();

    bf16x8 a[4], b[4];
    #pragma unroll
    for (int mi = 0; mi < 4; ++mi)
      a[mi] = *(const bf16x8*)&As[(wr*64 + mi*16 + mrow)*BK + krow*8];
    #pragma unroll
    for (int ni = 0; ni < 4; ++ni)
      b[ni] = *(const bf16x8*)&Bs[(wc*64 + ni*16 + mrow)*BK + krow*8];
    #pragma unroll
    for (int mi = 0; mi < 4; ++mi)
      #pragma unroll
      for (int ni = 0; ni < 4; ++ni)
        acc[mi][ni] = __builtin_amdgcn_mfma_f32_16x16x32_bf16(a[mi], b[ni], acc[mi][ni], 0, 0, 0);
    __syncthreads();
  }

  int row0 = blockIdx.y*BM + wr*64;
  int col0 = blockIdx.x*BN + wc*64;
  #pragma unroll
  for (int mi = 0; mi < 4; ++mi){
    #pragma unroll
    for (int ni = 0; ni < 4; ++ni){
      int col = col0 + ni*16 + mrow;
      float bv = HAS_BIAS ? bias[col] : 0.f;
      #pragma unroll
      for (int r = 0; r < 4; ++r){
        int row = row0 + mi*16 + krow*4 + r;
        float v = acc[mi][ni][r] + bv;
        if (RELU) v = fmaxf(v, 0.f);
        if (OUT_BF16) ((unsigned short*)Cp)[(long)row*N + col] = f2bf(v);
        else          ((float*)Cp)[(long)row*N + col] = v;
      }
    }
  }
}

// ---------------------------------------------------------------- V transpose
// V[g][j][e] (2048x128 bf16) -> Vt[g][e][j] (128x2048 bf16)
__global__ __launch_bounds__(256) void transpose_v(
    const unsigned short* __restrict__ V, unsigned short* __restrict__ Vt){
  __shared__ unsigned short t[32][33];
  int g = blockIdx.z;
  int j0 = blockIdx.x*32, e0 = blockIdx.y*32;
  int tx = threadIdx.x, ty = threadIdx.y;      // 32 x 8
  const unsigned short* Vg = V + (long)g*262144;
  unsigned short* Vtg = Vt + (long)g*262144;
  #pragma unroll
  for (int i = 0; i < 4; ++i)
    t[ty + 8*i][tx] = Vg[(long)(j0 + ty + 8*i)*128 + e0 + tx];
  __syncthreads();
  #pragma unroll
  for (int i = 0; i < 4; ++i)
    Vtg[(long)(e0 + ty + 8*i)*2048 + j0 + tx] = t[tx][ty + 8*i];
}

// ---------------------------------------------------------------- fused attention
// One block = one group (g) x 32 query rows. 8 waves, 512 threads.
// S stripe (32 x 2048) lives in LDS as bf16, XOR-swizzled: S[q][j ^ ((q&7)<<3)].
// Phase 1: S = scale * Q @ K^T (K B-frags direct from global, L2-hot)
// Phase 2: row softmax (fp32 stats), renormalized P -> back to LDS (bf16)
// Phase 3: ctx = P @ V (Vt B-frags direct from global); fp32 P stores to d_out
//          interleaved with the MFMA loop so the 537MB write drains under compute.
__global__ __launch_bounds__(512, 1) void attn_fused(
    const unsigned short* __restrict__ Q, const unsigned short* __restrict__ K,
    const unsigned short* __restrict__ Vt, float* __restrict__ P,
    unsigned short* __restrict__ CTX)
{
  __shared__ unsigned short S[32*2048];   // 128 KiB
  const int tid  = threadIdx.x;
  const int lane = tid & 63;
  const int wid  = tid >> 6;            // 0..7
  const int l15  = lane & 15;
  const int l4   = lane >> 4;
  const int g    = blockIdx.y;
  const int q0   = blockIdx.x * 32;
  const float scale = 0.08838834764831845f;  // 128^-0.5

  const unsigned short* Qb = Q  + (size_t)g*262144 + (size_t)q0*128;
  const unsigned short* Kb = K  + (size_t)g*262144;
  const unsigned short* Vb = Vt + (size_t)g*262144;
  float*                Pb = P  + (size_t)g*4194304 + (size_t)q0*2048;

  // ---- Q fragments (rows mi*16 + l15, k-groups l4*8)
  bf16x8 qa[2][4];
  #pragma unroll
  for (int mi = 0; mi < 2; ++mi)
    #pragma unroll
    for (int ks = 0; ks < 4; ++ks)
      qa[mi][ks] = *(const bf16x8*)(Qb + (size_t)(mi*16 + l15)*128 + ks*32 + l4*8);

  // ---- phase 1: this wave computes S cols [wid*256, wid*256+256)
  #pragma unroll 2
  for (int jf = 0; jf < 16; ++jf){
    const int j0 = wid*256 + jf*16;
    f32x4 a0 = {}, a1 = {};
    #pragma unroll
    for (int ks = 0; ks < 4; ++ks){
      bf16x8 b = *(const bf16x8*)(Kb + (size_t)(j0 + l15)*128 + ks*32 + l4*8);
      a0 = __builtin_amdgcn_mfma_f32_16x16x32_bf16(qa[0][ks], b, a0, 0, 0, 0);
      a1 = __builtin_amdgcn_mfma_f32_16x16x32_bf16(qa[1][ks], b, a1, 0, 0, 0);
    }
    const int jcol = j0 + l15;
    #pragma unroll
    for (int r = 0; r < 4; ++r){
      int qr = l4*4 + r;            // C-layout row (m-frag 0)
      S[qr*2048 + (jcol ^ ((qr&7)<<3))] = f2bf(a0[r]*scale);
      int q2 = 16 + qr;             // m-frag 1
      S[q2*2048 + (jcol ^ ((q2&7)<<3))] = f2bf(a1[r]*scale);
    }
  }
  __syncthreads();

  // ---- phase 2: softmax rows wid*4 .. wid*4+3 (all 64 lanes per row)
  #pragma unroll
  for (int rr = 0; rr < 4; ++rr){
    const int q_ = wid*4 + rr;
    const int sw = (q_&7)<<3;
    float v[32];
    float mx = -3.0e38f;
    #pragma unroll
    for (int i = 0; i < 8; ++i){
      bf16x4 t = *(const bf16x4*)&S[q_*2048 + ((i*256 + lane*4) ^ sw)];
      #pragma unroll
      for (int u = 0; u < 4; ++u){
        float f = bf2f((unsigned short)t[u]);
        v[i*4+u] = f;
        mx = fmaxf(mx, f);
      }
    }
    #pragma unroll
    for (int off = 32; off > 0; off >>= 1) mx = fmaxf(mx, __shfl_xor(mx, off, 64));
    float sum = 0.f;
    #pragma unroll
    for (int u = 0; u < 32; ++u){ v[u] = __expf(v[u] - mx); sum += v[u]; }
    #pragma unroll
    for (int off = 32; off > 0; off >>= 1) sum += __shfl_xor(sum, off, 64);
    const float inv = 1.f / sum;
    #pragma unroll
    for (int i = 0; i < 8; ++i){
      bf16x4 t;
      #pragma unroll
      for (int u = 0; u < 4; ++u) t[u] = (short)f2bf(v[i*4+u]*inv);
      *(bf16x4*)&S[q_*2048 + ((i*256 + lane*4) ^ sw)] = t;
    }
  }
  __syncthreads();

  // ---- phase 3: ctx = P @ V ; this wave owns e-cols [wid*16, wid*16+16)
  // interleave: 32 P-store chunks (fp32 -> d_out) across the 64 k-steps
  f32x4 c0 = {}, c1 = {};
  const int e0 = wid*16;
  const int m1 = 16 + l15;
  const int swA0 = (l15&7)<<3;       // same for m1 (row&7 identical)
  #pragma unroll 2
  for (int ks = 0; ks < 64; ++ks){
    bf16x8 b = *(const bf16x8*)(Vb + (size_t)(e0 + l15)*2048 + ks*32 + l4*8);
    const int kb = ks*32 + l4*8;
    bf16x8 p0 = *(const bf16x8*)&S[l15*2048 + (kb ^ swA0)];
    bf16x8 p1 = *(const bf16x8*)&S[m1*2048 + (kb ^ swA0)];
    c0 = __builtin_amdgcn_mfma_f32_16x16x32_bf16(p0, b, c0, 0, 0, 0);
    c1 = __builtin_amdgcn_mfma_f32_16x16x32_bf16(p1, b, c1, 0, 0, 0);
    if ((ks & 1) == 0){
      const int ci = ks >> 1;
      const int rr = ci >> 3, i = ci & 7;
      const int q_ = wid*4 + rr;
      const int cidx = (i*256 + lane*4) ^ ((q_&7)<<3);
      bf16x4 t = *(const bf16x4*)&S[q_*2048 + cidx];
      float4 o;
      o.x = bf2f((unsigned short)t[0]); o.y = bf2f((unsigned short)t[1]);
      o.z = bf2f((unsigned short)t[2]); o.w = bf2f((unsigned short)t[3]);
      *(float4*)(Pb + (size_t)q_*2048 + cidx) = o;
    }
  }
  // ---- ctx epilogue (flat [g][q][e] order == reference's raw reshape)
  #pragma unroll
  for (int r = 0; r < 4; ++r){
    int qr = l4*4 + r;
    CTX[(size_t)g*262144 + (size_t)(q0 + qr)*128      + e0 + l15] = f2bf(c0[r]);
    CTX[(size_t)g*262144 + (size_t)(q0 + 16 + qr)*128 + e0 + l15] = f2bf(c1[r]);
  }
}

// ---------------------------------------------------------------- LayerNorm
DEV float block_sum256(float v, float* red){
  #pragma unroll
  for (int off = 32; off > 0; off >>= 1) v += __shfl_xor(v, off, 64);
  int lane = threadIdx.x & 63, wid = threadIdx.x >> 6;
  if (lane == 0) red[wid] = v;
  __syncthreads();
  return (red[0]+red[1]) + (red[2]+red[3]);
}

template<bool WRITE_F32, bool WRITE_BF>
__global__ __launch_bounds__(256) void ln_residual(
    const float* __restrict__ X, const float* __restrict__ R,
    const float* __restrict__ gamma, const float* __restrict__ beta,
    float* __restrict__ outf, unsigned short* __restrict__ outb){
  __shared__ float red1[4], red2[4];
  long base = (long)blockIdx.x * 1024;
  int tid = threadIdx.x;
  float4 x = *(const float4*)(X + base + tid*4);
  float4 r = *(const float4*)(R + base + tid*4);
  float v[4] = {x.x+r.x, x.y+r.y, x.z+r.z, x.w+r.w};
  float s = (v[0]+v[1]) + (v[2]+v[3]);
  s = block_sum256(s, red1);
  float mean = s * (1.f/1024.f);
  float d[4] = {v[0]-mean, v[1]-mean, v[2]-mean, v[3]-mean};
  float sq = (d[0]*d[0]+d[1]*d[1]) + (d[2]*d[2]+d[3]*d[3]);
  sq = block_sum256(sq, red2);
  float rstd = rsqrtf(sq*(1.f/1024.f) + 1e-5f);
  float4 g4 = *(const float4*)(gamma + tid*4);
  float4 b4 = *(const float4*)(beta  + tid*4);
  float o[4] = { d[0]*rstd*g4.x + b4.x, d[1]*rstd*g4.y + b4.y,
                 d[2]*rstd*g4.z + b4.z, d[3]*rstd*g4.w + b4.w };
  if (WRITE_F32){
    float4 o4; o4.x=o[0]; o4.y=o[1]; o4.z=o[2]; o4.w=o[3];
    *(float4*)(outf + base + tid*4) = o4;
  }
  if (WRITE_BF){
    ushort4 ob; ob.x=f2bf(o[0]); ob.y=f2bf(o[1]); ob.z=f2bf(o[2]); ob.w=f2bf(o[3]);
    *(ushort4*)(outb + base + tid*4) = ob;
  }
}

// ---------------------------------------------------------------- host
extern "C" void kernel_launch(void* const* d_in, const int* in_sizes, int n_in,
                              void* d_out, int out_size, void* d_ws, size_t ws_size,
                              hipStream_t stream){
  const float* X   = (const float*)d_in[0];
  const float* Wq  = (const float*)d_in[1];
  const float* bq  = (const float*)d_in[2];
  const float* Wk  = (const float*)d_in[3];
  const float* bk  = (const float*)d_in[4];
  const float* Wv  = (const float*)d_in[5];
  const float* bv  = (const float*)d_in[6];
  const float* Wo  = (const float*)d_in[7];
  const float* bo  = (const float*)d_in[8];
  const float* g1  = (const float*)d_in[9];
  const float* b1n = (const float*)d_in[10];
  const float* W1  = (const float*)d_in[11];
  const float* b1  = (const float*)d_in[12];
  const float* W2  = (const float*)d_in[13];
  const float* b2  = (const float*)d_in[14];
  const float* g2  = (const float*)d_in[15];
  const float* b2n = (const float*)d_in[16];

  const int M = 8192, D = 1024, F = 2048;
  const long YSZ = (long)M * D;
  float* y_out = (float*)d_out;
  float* atten = (float*)d_out + YSZ;        // 32 x 2048 x 2048 fp32

  char* w = (char*)d_ws;
  auto alloc = [&](size_t bytes){ char* p = w; w += (bytes + 255) & ~(size_t)255; return p; };
  unsigned short* Xbf   = (unsigned short*)alloc((size_t)M*D*2);
  unsigned short* Wqbf  = (unsigned short*)alloc((size_t)D*D*2);
  unsigned short* Wkbf  = (unsigned short*)alloc((size_t)D*D*2);
  unsigned short* Wvbf  = (unsigned short*)alloc((size_t)D*D*2);
  unsigned short* Wobf  = (unsigned short*)alloc((size_t)D*D*2);
  unsigned short* W1bf  = (unsigned short*)alloc((size_t)F*D*2);
  unsigned short* W2bf  = (unsigned short*)alloc((size_t)D*F*2);
  unsigned short* Qbf   = (unsigned short*)alloc((size_t)M*D*2);
  unsigned short* Kbf   = (unsigned short*)alloc((size_t)M*D*2);
  unsigned short* Vbf   = (unsigned short*)alloc((size_t)M*D*2);
  unsigned short* Vtbf  = (unsigned short*)alloc((size_t)M*D*2);
  unsigned short* CTXbf = (unsigned short*)alloc((size_t)M*D*2);
  unsigned short* Hbf   = (unsigned short*)alloc((size_t)M*D*2);
  unsigned short* F1bf  = (unsigned short*)alloc((size_t)M*F*2);
  float*          Hf    = (float*)alloc((size_t)M*D*4);
  float*          TMP   = (float*)alloc((size_t)M*D*4);

  auto cvt = [&](const float* src, unsigned short* dst, int n){
    int blocks = (n/4 + 255)/256; if (blocks > 4096) blocks = 4096;
    cvt_f32_bf16<<<blocks, 256, 0, stream>>>(src, dst, n);
  };
  cvt(X,  Xbf,  M*D);
  cvt(Wq, Wqbf, D*D);  cvt(Wk, Wkbf, D*D);  cvt(Wv, Wvbf, D*D);  cvt(Wo, Wobf, D*D);
  cvt(W1, W1bf, F*D);  cvt(W2, W2bf, D*F);

  dim3 blk(256);

  // Q/K/V projections: [8192,1024] = X @ W^T + b  -> bf16
  gemm_bt<true,false,true><<<dim3(D/128, M/128), blk, 0, stream>>>(Xbf, Wqbf, bq, Qbf, D, D);
  gemm_bt<true,false,true><<<dim3(D/128, M/128), blk, 0, stream>>>(Xbf, Wkbf, bk, Kbf, D, D);
  gemm_bt<true,false,true><<<dim3(D/128, M/128), blk, 0, stream>>>(Xbf, Wvbf, bv, Vbf, D, D);

  // V -> Vt per group (j-contiguous rows for PV B-operand)
  transpose_v<<<dim3(64, 4, 32), dim3(32, 8), 0, stream>>>(Vbf, Vtbf);

  // fused attention: S -> softmax -> atten write + PV -> ctx
  attn_fused<<<dim3(64, 32), 512, 0, stream>>>(Qbf, Kbf, Vtbf, atten, CTXbf);

  // out = ctx @ Wo^T + bo -> TMP fp32
  gemm_bt<false,false,true><<<dim3(D/128, M/128), blk, 0, stream>>>(CTXbf, Wobf, bo, TMP, D, D);

  // h = LN1(X + out) -> Hf (fp32) + Hbf (bf16)
  ln_residual<true,true><<<M, 256, 0, stream>>>(X, TMP, g1, b1n, Hf, Hbf);

  // f1 = relu(h @ W1^T + b1) -> bf16
  gemm_bt<true,true,true><<<dim3(F/128, M/128), blk, 0, stream>>>(Hbf, W1bf, b1, F1bf, F, D);

  // f = f1 @ W2^T + b2 -> TMP fp32
  gemm_bt<false,false,true><<<dim3(D/128, M/128), blk, 0, stream>>>(F1bf, W2bf, b2, TMP, D, F);

  // y = LN2(h + f) -> d_out
  ln_residual<true,false><<<M, 256, 0, stream>>>(Hf, TMP, g2, b2n, y_out, nullptr);
}